// Round 12
// baseline (144.334 us; speedup 1.0000x reference)
//
#include <hip/hip_runtime.h>

// LDS forward collapsed to causal conv:
//   y[b,t,o] = sum_{d<=t} x[b,t-d] * K[d,o] + G[t,o]
//   K[d,o] = sum_s C[s,o] A[s]^d B[s]  (+ M[o,0,d-1] for d in 1..5)
//   G[t,o] = sum_s C[s,o] A[s]^{t+1} h0[s]
//
// R12 = ABLATION ROUND: exact R9 structure (best, 85.5us). k_main is
// templated: DUMMY=1 stores to a shared L2-resident 1MB scratch (same
// instruction stream, no DRAM store drain), DUMMY=0 is the real kernel.
// Launch order: prep, k_main<1>, k_main<0>.  dummy_cost = total - 85.5.

typedef __attribute__((ext_vector_type(8))) short short8v;
typedef __attribute__((ext_vector_type(4))) float float4v;

#define NB 16
#define SIG(e) ((e) + ((e) >> 3))   // pad: entry e -> slot e + e/8

static __device__ __forceinline__ unsigned short f2bf(float f) {
    union { float f; unsigned int u; } x; x.f = f;
    unsigned int r = x.u + 0x7fffu + ((x.u >> 16) & 1u);  // RNE
    return (unsigned short)(r >> 16);
}

// ---------------- prep: KT/G (blocks 0..1023) + XS (blocks 1024..1279) ----
__global__ __launch_bounds__(256) void k_prep(const float* __restrict__ A,
                                              const float* __restrict__ B,
                                              const float* __restrict__ h0,
                                              const float* __restrict__ C,
                                              const float* __restrict__ M,
                                              const float* __restrict__ x,
                                              unsigned short* __restrict__ KT,
                                              float* __restrict__ G,
                                              short8v* __restrict__ XS) {
    __shared__ float PBL[512][4];
    __shared__ float PHL[512][4];
    __shared__ float red[4][64][8];
    __shared__ unsigned short xs[512];
    const int tid = threadIdx.x;

    if (blockIdx.x < 1024) {
        const int d0 = (blockIdx.x & 127) * 4;
        const int oc = blockIdx.x >> 7;

        #pragma unroll
        for (int q = 0; q < 2; ++q) {
            int ss = tid + q * 256;
            float a = A[ss];
            float r = 1.0f, base = a;
            #pragma unroll
            for (int bit = 0; bit < 9; ++bit) {
                if (d0 & (1 << bit)) r *= base;
                base *= base;
            }
            float bs = B[ss], hs = h0[ss];
            #pragma unroll
            for (int j = 0; j < 4; ++j) {
                PBL[ss][j] = r * bs;
                PHL[ss][j] = r * a * hs;
                r *= a;
            }
        }
        __syncthreads();

        const int lane = tid & 63;
        const int sc   = tid >> 6;
        const int o    = oc * 64 + lane;
        float kt[4] = {0.f, 0.f, 0.f, 0.f};
        float gg[4] = {0.f, 0.f, 0.f, 0.f};
        for (int si = 0; si < 128; si += 8) {
            float c8[8];
            #pragma unroll
            for (int u = 0; u < 8; ++u)
                c8[u] = C[(sc * 128 + si + u) * 512 + o];
            #pragma unroll
            for (int u = 0; u < 8; ++u) {
                int s = sc * 128 + si + u;
                #pragma unroll
                for (int j = 0; j < 4; ++j) {
                    kt[j] = fmaf(PBL[s][j], c8[u], kt[j]);
                    gg[j] = fmaf(PHL[s][j], c8[u], gg[j]);
                }
            }
        }
        #pragma unroll
        for (int j = 0; j < 4; ++j) {
            red[sc][lane][j]     = kt[j];
            red[sc][lane][j + 4] = gg[j];
        }
        __syncthreads();
        if (sc == 0) {
            #pragma unroll
            for (int j = 0; j < 4; ++j) {
                float v  = red[0][lane][j] + red[1][lane][j]
                         + red[2][lane][j] + red[3][lane][j];
                float gv = red[0][lane][j+4] + red[1][lane][j+4]
                         + red[2][lane][j+4] + red[3][lane][j+4];
                int d = d0 + j;
                if (d >= 1 && d <= 5) v += M[o * 5 + (d - 1)];
                KT[o * 512 + d] = f2bf(v);
                G[d * 512 + o]  = gv;
            }
        }
    } else {
        const int b = blockIdx.x - 1024;
        #pragma unroll
        for (int q = 0; q < 2; ++q) {
            int i = tid * 2 + q;
            xs[i] = f2bf(x[b * 512 + 511 - i]);
        }
        __syncthreads();
        short8v* dst = XS + (size_t)b * 1216;
        for (int s2 = tid; s2 < 1216; s2 += 256) {
            if (s2 % 9 == 8 || s2 > 1150) dst[s2] = (short8v)(short)0;
        }
        #pragma unroll
        for (int q = 0; q < 4; ++q) {
            int e = tid * 4 + q;
            short8v v;
            #pragma unroll
            for (int jj = 0; jj < 8; ++jj) {
                int i = e + jj;
                v[jj] = (i < 512) ? (short)xs[i] : (short)0;
            }
            dst[SIG(e)] = v;
        }
    }
}

// ---------------- main (R9 structure): block = 512t x 32o, NB batches ------
template <int DUMMY>
__global__ __launch_bounds__(512, 2) void k_main(const short8v* __restrict__ XS,
                                                 const unsigned short* __restrict__ KT,
                                                 const float* __restrict__ G,
                                                 float* __restrict__ out,
                                                 float* __restrict__ DW) {
    __shared__ short8v xbuf[2][1216];     // 38 KB, sigma-padded octet tables

    const int bo0 = blockIdx.x * 32;
    const int b0  = blockIdx.y * NB;
    const int tid = threadIdx.x;
    const int lane = tid & 63;
    const int w    = tid >> 6;          // 0..7
    const int wm   = w >> 1, wn = w & 1;   // 4 wm x 2 wn
    const int t0w  = wm * 128;
    const int lrow = lane & 15;
    const int g    = lane >> 4;
    const int o0w  = bo0 + wn * 16;
    const int ocol = o0w + g * 4;

    // ---- prologue: batch-0 staging + B-regs + G-regs, one sync ----
    const short8v* s0 = XS + (size_t)b0 * 1216;
    short8v x0 = s0[tid], x1 = s0[tid + 512], x2;
    if (tid < 192) x2 = s0[tid + 1024];

    short8v bfr[16];                      // this wave's 16o x 512k B slice
    {
        const unsigned short* bp = KT + (o0w + lrow) * 512 + g * 8;
        #pragma unroll
        for (int ks = 0; ks < 16; ++ks)
            bfr[ks] = *(const short8v*)(bp + ks * 32);
    }

    float4v gacc[8];                      // batch-invariant G tile
    #pragma unroll
    for (int mi = 0; mi < 8; ++mi)
        gacc[mi] = *(const float4v*)(G + (t0w + mi * 16 + lrow) * 512 + ocol);

    xbuf[0][tid] = x0;
    xbuf[0][tid + 512] = x1;
    if (tid < 192) xbuf[0][tid + 1024] = x2;
    __syncthreads();

    const int E0 = 511 - t0w - lrow + g * 8;   // frag j at SIG(E0 + 16*j)

    int p = 0;
    for (int bi = 0; bi < NB; ++bi) {
        const int b = b0 + bi;

        // issue next batch's staging loads early (drain under MFMA loop)
        short8v nx0, nx1, nx2;
        if (bi + 1 < NB) {
            const short8v* s = XS + (size_t)(b + 1) * 1216;
            nx0 = s[tid];
            nx1 = s[tid + 512];
            if (tid < 192) nx2 = s[tid + 1024];
        }

        const short8v* xo = xbuf[p];

        float4v acc[8];
        #pragma unroll
        for (int mi = 0; mi < 8; ++mi) acc[mi] = (float4v)(0.0f);

        // A window: 8 frags j = 2ks-7 .. 2ks, 2 refills per k-step
        short8v aw[8];
        #pragma unroll
        for (int j = -7; j <= 0; ++j)
            aw[j & 7] = xo[SIG(E0 + 16 * j)];

        #pragma unroll
        for (int ks = 0; ks < 16; ++ks) {
            acc[7] = __builtin_amdgcn_mfma_f32_16x16x32_bf16(
                bfr[ks], aw[(2 * ks - 7) & 7], acc[7], 0, 0, 0);
            acc[6] = __builtin_amdgcn_mfma_f32_16x16x32_bf16(
                bfr[ks], aw[(2 * ks - 6) & 7], acc[6], 0, 0, 0);
            if (ks < 15) {
                aw[(2 * ks + 1) & 7] = xo[SIG(E0 + 16 * (2 * ks + 1))];
                aw[(2 * ks + 2) & 7] = xo[SIG(E0 + 16 * (2 * ks + 2))];
            }
            #pragma unroll
            for (int mi = 5; mi >= 0; --mi)
                acc[mi] = __builtin_amdgcn_mfma_f32_16x16x32_bf16(
                    bfr[ks], aw[(2 * ks - mi) & 7], acc[mi], 0, 0, 0);
        }

        // epilogue: DUMMY stores to shared L2-resident 1MB scratch (same
        // in-batch address pattern, no b-offset); real stores to out.
        float* op = DUMMY ? DW : (out + (size_t)b * 262144);
        #pragma unroll
        for (int mi = 0; mi < 8; ++mi) {
            const int t = t0w + mi * 16 + lrow;
            *(float4v*)(op + t * 512 + ocol) = acc[mi] + gacc[mi];
        }

        // write next buffer; lgkm-only barrier so global stores keep draining
        if (bi + 1 < NB) {
            short8v* xw = xbuf[p ^ 1];
            xw[tid] = nx0;
            xw[tid + 512] = nx1;
            if (tid < 192) xw[tid + 1024] = nx2;
            asm volatile("s_waitcnt lgkmcnt(0)" ::: "memory");
            __builtin_amdgcn_s_barrier();
            p ^= 1;
        }
    }
}

extern "C" void kernel_launch(void* const* d_in, const int* in_sizes, int n_in,
                              void* d_out, int out_size, void* d_ws, size_t ws_size,
                              hipStream_t stream) {
    const float* x  = (const float*)d_in[0];   // [256,512,1]
    const float* A  = (const float*)d_in[1];   // [512]
    const float* B  = (const float*)d_in[2];   // [1,512]
    const float* C  = (const float*)d_in[3];   // [512,512]
    const float* M  = (const float*)d_in[4];   // [512,1,5]
    const float* h0 = (const float*)d_in[5];   // [512]
    float* out = (float*)d_out;

    char* ws = (char*)d_ws;
    unsigned short* KT = (unsigned short*)ws;                      // 512 KB
    float*          G  = (float*)(ws + (1u << 19));                // 1 MB
    short8v*        XS = (short8v*)(ws + (1u << 19) + (1u << 20)); // ~4.75 MB
    float*          DW = (float*)(ws + (7u << 20));                // 1 MB dummy

    k_prep<<<1280, 256, 0, stream>>>(A, B, h0, C, M, x, KT, G, XS);
    k_main<1><<<dim3(16, 16), 512, 0, stream>>>(XS, KT, G, out, DW);  // ablation twin
    k_main<0><<<dim3(16, 16), 512, 0, stream>>>(XS, KT, G, out, DW);  // real
}

// Round 13
// 87.085 us; speedup vs baseline: 1.6574x; 1.6574x over previous
//
#include <hip/hip_runtime.h>

// LDS forward collapsed to causal conv:
//   y[b,t,o] = sum_{d<=t} x[b,t-d] * K[d,o] + G[t,o]
//   K[d,o] = sum_s C[s,o] A[s]^d B[s]  (+ M[o,0,d-1] for d in 1..5)
//   G[t,o] = sum_s C[s,o] A[s]^{t+1} h0[s]
//
// R13: 512 blocks of 256 threads (4 waves of 64t x 32o) = 2 blocks/CU.
// The two co-resident blocks barrier INDEPENDENTLY -> one block's epilogue/
// barrier/staging slides under the other's MFMA loop (R12 ablation showed
// 26us of lockstep-barrier idle at 1 block/CU). B-frags in regs (128 VGPR),
// Toeplitz A-frags from LDS octet table (6-slot rolling window). Staging via
// global_load_lds; counted vmcnt(8) barrier keeps stores draining. setprio(1)
// around MFMA cluster (2 independent blocks/CU -> T5's regime).

typedef __attribute__((ext_vector_type(8))) short short8v;
typedef __attribute__((ext_vector_type(4))) float float4v;

#define NB 16
#define SIG(e) ((e) + ((e) >> 3))           // pad: entry e -> slot e + e/8
#define AWI(j) ((((j) % 6) + 6) % 6)        // rolling window slot (compile-time)

static __device__ __forceinline__ unsigned short f2bf(float f) {
    union { float f; unsigned int u; } x; x.f = f;
    unsigned int r = x.u + 0x7fffu + ((x.u >> 16) & 1u);  // RNE
    return (unsigned short)(r >> 16);
}

// ---------------- prep: KT/G (blocks 0..1023) + XS (blocks 1024..1279) ----
__global__ __launch_bounds__(256) void k_prep(const float* __restrict__ A,
                                              const float* __restrict__ B,
                                              const float* __restrict__ h0,
                                              const float* __restrict__ C,
                                              const float* __restrict__ M,
                                              const float* __restrict__ x,
                                              unsigned short* __restrict__ KT,
                                              float* __restrict__ G,
                                              short8v* __restrict__ XS) {
    __shared__ float PBL[512][4];
    __shared__ float PHL[512][4];
    __shared__ float red[4][64][8];
    __shared__ unsigned short xs[512];
    const int tid = threadIdx.x;

    if (blockIdx.x < 1024) {
        const int d0 = (blockIdx.x & 127) * 4;
        const int oc = blockIdx.x >> 7;

        #pragma unroll
        for (int q = 0; q < 2; ++q) {
            int ss = tid + q * 256;
            float a = A[ss];
            float r = 1.0f, base = a;
            #pragma unroll
            for (int bit = 0; bit < 9; ++bit) {
                if (d0 & (1 << bit)) r *= base;
                base *= base;
            }
            float bs = B[ss], hs = h0[ss];
            #pragma unroll
            for (int j = 0; j < 4; ++j) {
                PBL[ss][j] = r * bs;
                PHL[ss][j] = r * a * hs;
                r *= a;
            }
        }
        __syncthreads();

        const int lane = tid & 63;
        const int sc   = tid >> 6;
        const int o    = oc * 64 + lane;
        float kt[4] = {0.f, 0.f, 0.f, 0.f};
        float gg[4] = {0.f, 0.f, 0.f, 0.f};
        for (int si = 0; si < 128; si += 8) {
            float c8[8];
            #pragma unroll
            for (int u = 0; u < 8; ++u)
                c8[u] = C[(sc * 128 + si + u) * 512 + o];
            #pragma unroll
            for (int u = 0; u < 8; ++u) {
                int s = sc * 128 + si + u;
                #pragma unroll
                for (int j = 0; j < 4; ++j) {
                    kt[j] = fmaf(PBL[s][j], c8[u], kt[j]);
                    gg[j] = fmaf(PHL[s][j], c8[u], gg[j]);
                }
            }
        }
        #pragma unroll
        for (int j = 0; j < 4; ++j) {
            red[sc][lane][j]     = kt[j];
            red[sc][lane][j + 4] = gg[j];
        }
        __syncthreads();
        if (sc == 0) {
            #pragma unroll
            for (int j = 0; j < 4; ++j) {
                float v  = red[0][lane][j] + red[1][lane][j]
                         + red[2][lane][j] + red[3][lane][j];
                float gv = red[0][lane][j+4] + red[1][lane][j+4]
                         + red[2][lane][j+4] + red[3][lane][j+4];
                int d = d0 + j;
                if (d >= 1 && d <= 5) v += M[o * 5 + (d - 1)];
                KT[o * 512 + d] = f2bf(v);
                G[d * 512 + o]  = gv;
            }
        }
    } else {
        const int b = blockIdx.x - 1024;
        #pragma unroll
        for (int q = 0; q < 2; ++q) {
            int i = tid * 2 + q;
            xs[i] = f2bf(x[b * 512 + 511 - i]);
        }
        __syncthreads();
        short8v* dst = XS + (size_t)b * 1216;
        for (int s2 = tid; s2 < 1216; s2 += 256) {
            if (s2 % 9 == 8 || s2 > 1150) dst[s2] = (short8v)(short)0;
        }
        #pragma unroll
        for (int q = 0; q < 4; ++q) {
            int e = tid * 4 + q;
            short8v v;
            #pragma unroll
            for (int jj = 0; jj < 8; ++jj) {
                int i = e + jj;
                v[jj] = (i < 512) ? (short)xs[i] : (short)0;
            }
            dst[SIG(e)] = v;
        }
    }
}

// ---------------- main: 512 blocks x 256 thr, block = 256t x 32o -----------
__global__ __launch_bounds__(256, 2) void k_main(const short8v* __restrict__ XS,
                                                 const unsigned short* __restrict__ KT,
                                                 const float* __restrict__ G,
                                                 float* __restrict__ out) {
    __shared__ short8v xbuf[2][1216];     // 38 KB, sigma-padded octet tables

    const int bo0 = blockIdx.x * 32;
    const int bt0 = blockIdx.y * 256;
    const int b0  = blockIdx.z * NB;
    const int tid = threadIdx.x;
    const int lane = tid & 63;
    const int wv   = tid >> 6;          // 0..3 -> t-chunk of 64
    const int t0w  = bt0 + wv * 64;
    const int lrow = lane & 15;
    const int g    = lane >> 4;

    // ---- prologue: stage batch 0 via global_load_lds, B-regs, G-regs ----
    {
        const short8v* src = XS + (size_t)b0 * 1216;
        for (int c = wv; c < 19; c += 4)
            __builtin_amdgcn_global_load_lds(
                (const __attribute__((address_space(1))) void*)(src + c * 64 + lane),
                (__attribute__((address_space(3))) void*)(&xbuf[0][c * 64]),
                16, 0, 0);
    }

    short8v bfr[2][16];                   // block's full 32-o B slice (128 VGPR)
    #pragma unroll
    for (int ni = 0; ni < 2; ++ni) {
        const unsigned short* bp = KT + (bo0 + ni * 16 + lrow) * 512 + g * 8;
        #pragma unroll
        for (int ks = 0; ks < 16; ++ks)
            bfr[ni][ks] = *(const short8v*)(bp + ks * 32);
    }

    float4v gacc[4][2];                   // batch-invariant G tile
    #pragma unroll
    for (int mi = 0; mi < 4; ++mi)
        #pragma unroll
        for (int ni = 0; ni < 2; ++ni)
            gacc[mi][ni] = *(const float4v*)(G + (t0w + mi * 16 + lrow) * 512
                                               + bo0 + ni * 16 + g * 4);

    asm volatile("s_waitcnt vmcnt(0)" ::: "memory");
    __builtin_amdgcn_s_barrier();

    const int E0 = 511 - t0w - lrow + g * 8;   // frag j at SIG(E0 + 16*j)

    int p = 0;
    for (int bi = 0; bi < NB; ++bi) {
        const int b = b0 + bi;

        // issue next batch's staging FIRST (oldest in vmcnt order)
        if (bi + 1 < NB) {
            const short8v* src = XS + (size_t)(b + 1) * 1216;
            short8v* dstb = xbuf[p ^ 1];
            for (int c = wv; c < 19; c += 4)
                __builtin_amdgcn_global_load_lds(
                    (const __attribute__((address_space(1))) void*)(src + c * 64 + lane),
                    (__attribute__((address_space(3))) void*)(dstb + c * 64),
                    16, 0, 0);
        }

        const short8v* xo = xbuf[p];

        float4v acc[4][2];
        #pragma unroll
        for (int mi = 0; mi < 4; ++mi)
            #pragma unroll
            for (int ni = 0; ni < 2; ++ni)
                acc[mi][ni] = (float4v)(0.0f);

        // A window: frags j = 2ks-3 .. 2ks live, 2 refills per k-step
        short8v aw[6];
        #pragma unroll
        for (int j = -3; j <= 0; ++j)
            aw[AWI(j)] = xo[SIG(E0 + 16 * j)];

        __builtin_amdgcn_s_setprio(1);
        #pragma unroll
        for (int ks = 0; ks < 16; ++ks) {
            acc[3][0] = __builtin_amdgcn_mfma_f32_16x16x32_bf16(
                bfr[0][ks], aw[AWI(2 * ks - 3)], acc[3][0], 0, 0, 0);
            acc[3][1] = __builtin_amdgcn_mfma_f32_16x16x32_bf16(
                bfr[1][ks], aw[AWI(2 * ks - 3)], acc[3][1], 0, 0, 0);
            acc[2][0] = __builtin_amdgcn_mfma_f32_16x16x32_bf16(
                bfr[0][ks], aw[AWI(2 * ks - 2)], acc[2][0], 0, 0, 0);
            acc[2][1] = __builtin_amdgcn_mfma_f32_16x16x32_bf16(
                bfr[1][ks], aw[AWI(2 * ks - 2)], acc[2][1], 0, 0, 0);
            if (ks < 15) {
                aw[AWI(2 * ks + 1)] = xo[SIG(E0 + 16 * (2 * ks + 1))];
                aw[AWI(2 * ks + 2)] = xo[SIG(E0 + 16 * (2 * ks + 2))];
            }
            acc[1][0] = __builtin_amdgcn_mfma_f32_16x16x32_bf16(
                bfr[0][ks], aw[AWI(2 * ks - 1)], acc[1][0], 0, 0, 0);
            acc[1][1] = __builtin_amdgcn_mfma_f32_16x16x32_bf16(
                bfr[1][ks], aw[AWI(2 * ks - 1)], acc[1][1], 0, 0, 0);
            acc[0][0] = __builtin_amdgcn_mfma_f32_16x16x32_bf16(
                bfr[0][ks], aw[AWI(2 * ks)], acc[0][0], 0, 0, 0);
            acc[0][1] = __builtin_amdgcn_mfma_f32_16x16x32_bf16(
                bfr[1][ks], aw[AWI(2 * ks)], acc[0][1], 0, 0, 0);
        }
        __builtin_amdgcn_s_setprio(0);

        // epilogue stores (newest in vmcnt order; drain across the barrier)
        float* op = out + (size_t)b * 262144;
        #pragma unroll
        for (int mi = 0; mi < 4; ++mi) {
            const int t = t0w + mi * 16 + lrow;
            float* rp = op + t * 512 + bo0 + g * 4;
            *(float4v*)(rp)      = acc[mi][0] + gacc[mi][0];
            *(float4v*)(rp + 16) = acc[mi][1] + gacc[mi][1];
        }

        // counted barrier: waits stage-glds (oldest) retired; the 8 epilogue
        // stores stay in flight and drain under the next MFMA loop.
        if (bi + 1 < NB) {
            asm volatile("s_waitcnt vmcnt(8)" ::: "memory");
            __builtin_amdgcn_s_barrier();
            p ^= 1;
        }
    }
}

extern "C" void kernel_launch(void* const* d_in, const int* in_sizes, int n_in,
                              void* d_out, int out_size, void* d_ws, size_t ws_size,
                              hipStream_t stream) {
    const float* x  = (const float*)d_in[0];   // [256,512,1]
    const float* A  = (const float*)d_in[1];   // [512]
    const float* B  = (const float*)d_in[2];   // [1,512]
    const float* C  = (const float*)d_in[3];   // [512,512]
    const float* M  = (const float*)d_in[4];   // [512,1,5]
    const float* h0 = (const float*)d_in[5];   // [512]
    float* out = (float*)d_out;

    char* ws = (char*)d_ws;
    unsigned short* KT = (unsigned short*)ws;                      // 512 KB
    float*          G  = (float*)(ws + (1u << 19));                // 1 MB
    short8v*        XS = (short8v*)(ws + (1u << 19) + (1u << 20)); // ~4.75 MB

    k_prep<<<1280, 256, 0, stream>>>(A, B, h0, C, M, x, KT, G, XS);
    k_main<<<dim3(16, 2, 16), 256, 0, stream>>>(XS, KT, G, out);
}